// Round 1
// 1841.367 us; speedup vs baseline: 1.0275x; 1.0275x over previous
//
#include <hip/hip_runtime.h>

#define M_ROWS 8192
#define K_DIM  2048
#define N_SAE  16384
#define TOPK   64
#define WEPS   0.027f   // 2*eps: eps = 6*sigma_gemm(2e-3) + fp16 half-ulp(1e-3) ~ 1.3e-2

typedef __attribute__((ext_vector_type(8))) short bf16x8;
typedef __attribute__((ext_vector_type(4))) float f32x4;

__device__ __forceinline__ unsigned short f2bf(float f) {
  unsigned u = __float_as_uint(f);
  u += 0x7FFFu + ((u >> 16) & 1u);   // round-to-nearest-even
  return (unsigned short)(u >> 16);
}

__device__ __forceinline__ float key2float(unsigned k) {
  unsigned short bits = (k & 0x8000u) ? (unsigned short)(k ^ 0x8000u)
                                      : (unsigned short)(~k);
  _Float16 h;
  __builtin_memcpy(&h, &bits, 2);
  return (float)h;
}

__device__ __forceinline__ void gload16(const void* g, void* l) {
  __builtin_amdgcn_global_load_lds(
      (const __attribute__((address_space(1))) unsigned int*)g,
      (__attribute__((address_space(3))) unsigned int*)l, 16, 0, 0);
}

// ---------------- kernel 0a: x fp32 -> bf16 ----------------
__global__ __launch_bounds__(256) void k_convx(const float* __restrict__ x,
                                               unsigned short* __restrict__ xb) {
  const long i = ((long)blockIdx.x * 256 + threadIdx.x) * 4;
  float4 v = *(const float4*)(x + i);
  ushort4 o;
  o.x = f2bf(v.x); o.y = f2bf(v.y); o.z = f2bf(v.z); o.w = f2bf(v.w);
  *(ushort4*)(xb + i) = o;
}

// ---------------- kernel 0b: W_enc [K,N] -> W_encT [N,K] (f32 + bf16) ----------------
__global__ __launch_bounds__(256) void k_transpose(const float* __restrict__ W,
                                                   float* __restrict__ Wt,
                                                   unsigned short* __restrict__ Wtb) {
  __shared__ float tile[32][33];
  const int nb = blockIdx.x * 32;
  const int kb = blockIdx.y * 32;
  const int tx = threadIdx.x & 31;
  const int ty = threadIdx.x >> 5;
#pragma unroll
  for (int i = 0; i < 32; i += 8)
    tile[ty + i][tx] = W[(long)(kb + ty + i) * N_SAE + nb + tx];
  __syncthreads();
#pragma unroll
  for (int i = 0; i < 32; i += 8) {
    float v = tile[tx][ty + i];
    long o = (long)(nb + ty + i) * K_DIM + kb + tx;
    Wt[o] = v;
    Wtb[o] = f2bf(v);
  }
}

// ---------------- kernel 1: bf16 MFMA GEMM, 256x256 tile, 3-deep counted-vmcnt pipeline ----------------
// pre = x @ W_enc + b_enc -> fp16.  A=[M,K] bf16 row-major, B=[N,K] bf16 (W_enc^T).
// LDS: 4 buffers x (A 16KB + B 16KB) = 128 KB. Stage lead = 3 K-tiles, steady vmcnt(8).
// Swizzle: 16B chunk within 64B row XOR'd by (r&3)^((r>>2)&3); linear LDS dest + inverse-
// swizzled global source (global_load_lds writes linearly), swizzled ds_read addresses.
__global__ __launch_bounds__(512, 2) void k_gemm(const unsigned short* __restrict__ A,
                                                 const unsigned short* __restrict__ B,
                                                 const float* __restrict__ b_enc,
                                                 _Float16* __restrict__ C) {
  __shared__ unsigned short lds[4 * 16384];   // 128 KiB
  const int t = threadIdx.x;
  const int lane = t & 63;
  const int w = t >> 6;
  const int wm = w >> 2, wn = w & 3;          // 2M x 4N waves
  const int ml = lane & 15, kh = lane >> 4;

  // XCD-aware bijective swizzle (2048 % 8 == 0)
  const int bid = blockIdx.x;
  const int swz = (bid & 7) * 256 + (bid >> 3);
  const int bn = (swz & 63) * 256;
  const int bm = (swz >> 6) * 256;

  // staging: thread t covers chunk t (rows 0..127) and chunk t+512 (rows 128..255)
  const int r0 = t >> 2;
  const int c0 = (t & 3) ^ (r0 & 3) ^ ((r0 >> 2) & 3);
  const int r1 = r0 + 128;
  const int c1 = (t & 3) ^ (r1 & 3) ^ ((r1 >> 2) & 3);
  const unsigned short* gA0 = A + (long)(bm + r0) * K_DIM + c0 * 8;
  const unsigned short* gA1 = A + (long)(bm + r1) * K_DIM + c1 * 8;
  const unsigned short* gB0 = B + (long)(bn + r0) * K_DIM + c0 * 8;
  const unsigned short* gB1 = B + (long)(bn + r1) * K_DIM + c1 * 8;
  char* lb = (char*)lds;
  const int dA0 = t * 16,          dA1 = 8192 + t * 16;
  const int dB0 = 16384 + t * 16,  dB1 = 24576 + t * 16;

  // read offsets: XOR term is mi/ni-independent (mi*16, wm*128 are 0 mod 4 after >>2)
  const int fx = (ml & 3) ^ ((ml >> 2) & 3);
  const int offA0 = (wm * 128 + ml) * 64 + ((kh ^ fx) * 16);
  const int offB0 = 16384 + (wn * 64 + ml) * 64 + ((kh ^ fx) * 16);

  f32x4 acc[8][4] = {};

#define STAGE(kt_) do {                         \
    const int bb_ = ((kt_) & 3) * 32768;        \
    const int ko_ = (kt_) * 32;                 \
    gload16(gA0 + ko_, lb + bb_ + dA0);         \
    gload16(gA1 + ko_, lb + bb_ + dA1);         \
    gload16(gB0 + ko_, lb + bb_ + dB0);         \
    gload16(gB1 + ko_, lb + bb_ + dB1);         \
  } while (0)

  STAGE(0);
  asm volatile("" ::: "memory");
  STAGE(1);
  asm volatile("" ::: "memory");
  STAGE(2);

  for (int kt = 0; kt < 64; ++kt) {
    // outstanding before barrier: tiles kt..min(kt+2,63) -> wait until tile kt landed
    if (kt < 62)       asm volatile("s_waitcnt vmcnt(8)" ::: "memory");
    else if (kt == 62) asm volatile("s_waitcnt vmcnt(4)" ::: "memory");
    else               asm volatile("s_waitcnt vmcnt(0)" ::: "memory");
    __builtin_amdgcn_s_barrier();
    asm volatile("" ::: "memory");
    if (kt < 61) STAGE(kt + 3);   // overwrites buffer (kt-1)&3: reads done before this barrier
    const char* bp = lb + (kt & 3) * 32768;
    bf16x8 af[8], bv[4];
#pragma unroll
    for (int mi = 0; mi < 8; ++mi) af[mi] = *(const bf16x8*)(bp + offA0 + mi * 1024);
#pragma unroll
    for (int ni = 0; ni < 4; ++ni) bv[ni] = *(const bf16x8*)(bp + offB0 + ni * 1024);
    __builtin_amdgcn_s_setprio(1);
#pragma unroll
    for (int mi = 0; mi < 8; ++mi)
#pragma unroll
      for (int ni = 0; ni < 4; ++ni)
        acc[mi][ni] = __builtin_amdgcn_mfma_f32_16x16x32_bf16(af[mi], bv[ni], acc[mi][ni], 0, 0, 0);
    __builtin_amdgcn_s_setprio(0);
  }
#undef STAGE

  // epilogue: C/D layout col=lane&15, row=(lane>>4)*4+reg  [m89-verified]
#pragma unroll
  for (int ni = 0; ni < 4; ++ni) {
    const int gn = bn + wn * 64 + ni * 16 + ml;
    const float bias = b_enc[gn];
#pragma unroll
    for (int mi = 0; mi < 8; ++mi) {
      const int gm0 = bm + wm * 128 + mi * 16 + kh * 4;
#pragma unroll
      for (int rr = 0; rr < 4; ++rr)
        C[(long)(gm0 + rr) * N_SAE + gn] = (_Float16)(acc[mi][ni][rr] + bias);
    }
  }
}

// ---------------- kernel 2: exact 64th-largest threshold + definite/ambiguous split ----------------
__global__ __launch_bounds__(256) void k_select(const unsigned short* __restrict__ pre,
                                                int* __restrict__ def_idx,
                                                int* __restrict__ amb_idx,
                                                int* __restrict__ counts) {
  __shared__ unsigned short keys[16384];  // 32 KB
  __shared__ unsigned int hist[256];
  __shared__ unsigned int scan[256];
  __shared__ unsigned int sc[8];
  const long row = blockIdx.x;
  const int t = threadIdx.x;
  const uint4* src = (const uint4*)(pre + row * N_SAE);
  uint4* kdst = (uint4*)keys;
#pragma unroll
  for (int i = 0; i < 8; i++) {
    uint4 v = src[i * 256 + t];
    uint4 o;
    unsigned s;
    s = v.x & 0x80008000u; o.x = v.x ^ (0x80008000u | ((s >> 15) * 0x7FFFu));
    s = v.y & 0x80008000u; o.y = v.y ^ (0x80008000u | ((s >> 15) * 0x7FFFu));
    s = v.z & 0x80008000u; o.z = v.z ^ (0x80008000u | ((s >> 15) * 0x7FFFu));
    s = v.w & 0x80008000u; o.w = v.w ^ (0x80008000u | ((s >> 15) * 0x7FFFu));
    kdst[i * 256 + t] = o;
  }
  hist[t] = 0;
  if (t < 8) sc[t] = 0;
  __syncthreads();
  for (int i = 0; i < 64; i++) {
    unsigned k = keys[i * 256 + t];
    atomicAdd(&hist[k >> 8], 1u);
  }
  __syncthreads();
  scan[t] = hist[t];
  __syncthreads();
  for (int off = 1; off < 256; off <<= 1) {   // suffix sum
    unsigned v = (t + off < 256) ? scan[t + off] : 0u;
    __syncthreads();
    scan[t] += v;
    __syncthreads();
  }
  if (scan[t] >= TOPK && (t == 255 || scan[t + 1] < TOPK)) {
    sc[0] = (unsigned)t;
    sc[1] = (t == 255) ? 0u : scan[t + 1];
  }
  __syncthreads();
  const unsigned bstar = sc[0];
  const unsigned H = sc[1];
  hist[t] = 0;
  __syncthreads();
  for (int i = 0; i < 64; i++) {
    unsigned k = keys[i * 256 + t];
    if ((k >> 8) == bstar) atomicAdd(&hist[k & 255u], 1u);
  }
  __syncthreads();
  scan[t] = hist[t];
  __syncthreads();
  for (int off = 1; off < 256; off <<= 1) {
    unsigned v = (t + off < 256) ? scan[t + off] : 0u;
    __syncthreads();
    scan[t] += v;
    __syncthreads();
  }
  if (H + scan[t] >= TOPK && (t == 255 || H + scan[t + 1] < TOPK)) sc[2] = (unsigned)t;
  __syncthreads();
  const unsigned T = (bstar << 8) | sc[2];      // exact 64th-largest fp16 key
  const float tf = key2float(T);
  const float lo = tf - WEPS;
  const float hi = tf + WEPS;
  for (int i = 0; i < 64; i++) {
    unsigned k = keys[i * 256 + t];
    float vf = key2float(k);
    if (vf > hi) {                               // provably in true top-64 (ndef <= 63)
      unsigned p = atomicAdd(&sc[3], 1u);
      def_idx[row * 64 + p] = i * 256 + t;
    } else if (vf >= lo) {                       // ambiguous: needs exact recompute
      unsigned p = atomicAdd(&sc[4], 1u);
      if (p < 64) amb_idx[row * 64 + p] = i * 256 + t;
    }
  }
  __syncthreads();
  if (t == 0) {
    counts[row * 2]     = (int)sc[3];
    counts[row * 2 + 1] = (int)(sc[4] < 64u ? sc[4] : 64u);
  }
}

// ---------------- kernel 3: f64 recompute of ambiguous set only + exact boundary ranking ----------------
__global__ __launch_bounds__(256) void k_exact2(const float* __restrict__ x,
                                                const float* __restrict__ Wt,
                                                const float* __restrict__ b_enc,
                                                const _Float16* __restrict__ pre,
                                                const int* __restrict__ def_idx,
                                                const int* __restrict__ amb_idx,
                                                const int* __restrict__ counts,
                                                int* __restrict__ tidx,
                                                float* __restrict__ tact) {
  __shared__ float xs[2048];
  __shared__ double vals[64];
  __shared__ int idxs[64];
  const int row = blockIdx.x;
  const int t = threadIdx.x;
  {
    const float4* src = (const float4*)(x + (long)row * K_DIM);
    ((float4*)xs)[t] = src[t];
    ((float4*)xs)[t + 256] = src[t + 256];
  }
  const int ndef = counts[row * 2];
  const int namb = counts[row * 2 + 1];
  if (t < 64) {
    idxs[t] = (t < namb) ? amb_idx[row * 64 + t] : -1;
    vals[t] = -1e300;
  }
  __syncthreads();
  const int wave = t >> 6, lane = t & 63;
  for (int c = wave; c < namb; c += 4) {
    const int f = idxs[c];
    const float4* w = (const float4*)(Wt + (long)f * K_DIM);
    const float4* xv4 = (const float4*)xs;
    double s = 0.0;
#pragma unroll
    for (int j = 0; j < 8; j++) {
      float4 wv = w[j * 64 + lane];
      float4 xv = xv4[j * 64 + lane];
      s += (double)wv.x * (double)xv.x;
      s += (double)wv.y * (double)xv.y;
      s += (double)wv.z * (double)xv.z;
      s += (double)wv.w * (double)xv.w;
    }
#pragma unroll
    for (int off = 32; off > 0; off >>= 1) s += __shfl_down(s, off);
    if (lane == 0) vals[c] = s + (double)b_enc[f];
  }
  __syncthreads();
  // bitonic sort descending over 64 (value, idx)
  for (int kk = 2; kk <= 64; kk <<= 1) {
    for (int j = kk >> 1; j > 0; j >>= 1) {
      if (t < 64) {
        const int p = t ^ j;
        if (p > t) {
          const bool up = ((t & kk) == 0);
          double a = vals[t], b = vals[p];
          if (up ? (a < b) : (a > b)) {
            vals[t] = b; vals[p] = a;
            int tmp = idxs[t]; idxs[t] = idxs[p]; idxs[p] = tmp;
          }
        }
      }
      __syncthreads();
    }
  }
  // outputs: ndef definite (fp16 approx values) + (64-ndef) best ambiguous (exact values)
  if (t < ndef) {
    const int f = def_idx[row * 64 + t];
    const float v = (float)pre[(long)row * N_SAE + f];
    tidx[row * TOPK + t] = f;
    tact[row * TOPK + t] = v > 0.f ? v : 0.f;
  }
  const int need = TOPK - ndef;
  if (t < need) {
    int f = idxs[t];
    double v = vals[t];
    if (f < 0) { f = 0; v = 0.0; }   // unreachable guard
    tidx[row * TOPK + ndef + t] = f;
    tact[row * TOPK + ndef + t] = (float)(v > 0.0 ? v : 0.0);
  }
}

// ---------------- kernel 4: sparse decode, recon = acts @ W_dec + b_dec ----------------
__global__ __launch_bounds__(256) void k_decode(const float* __restrict__ Wd,
                                                const float* __restrict__ b_dec,
                                                const int* __restrict__ tidx,
                                                const float* __restrict__ tact,
                                                float* __restrict__ out) {
  __shared__ int fid[TOPK];
  __shared__ float fac[TOPK];
  const int row = blockIdx.x, t = threadIdx.x;
  if (t < TOPK) {
    fid[t] = tidx[row * TOPK + t];
    fac[t] = tact[row * TOPK + t];
  }
  __syncthreads();
  float4 acc0 = ((const float4*)b_dec)[t * 2];
  float4 acc1 = ((const float4*)b_dec)[t * 2 + 1];
  for (int i = 0; i < TOPK; i++) {
    const float a = fac[i];
    const float4* w = (const float4*)(Wd + (long)fid[i] * K_DIM) + t * 2;
    float4 w0 = w[0], w1 = w[1];
    acc0.x += a * w0.x; acc0.y += a * w0.y; acc0.z += a * w0.z; acc0.w += a * w0.w;
    acc1.x += a * w1.x; acc1.y += a * w1.y; acc1.z += a * w1.z; acc1.w += a * w1.w;
  }
  float4* o = (float4*)(out + (long)row * K_DIM);
  o[t * 2] = acc0;
  o[t * 2 + 1] = acc1;
}

extern "C" void kernel_launch(void* const* d_in, const int* in_sizes, int n_in,
                              void* d_out, int out_size, void* d_ws, size_t ws_size,
                              hipStream_t stream) {
  const float* x     = (const float*)d_in[0];
  const float* W_enc = (const float*)d_in[1];
  const float* W_dec = (const float*)d_in[2];
  const float* b_enc = (const float*)d_in[3];
  const float* b_dec = (const float*)d_in[4];
  float* out = (float*)d_out;
  char* ws = (char*)d_ws;

  // layout (fits in the round-1-proven 488 MB):
  const size_t OFF_WT   = 0;            // W_encT f32   : 128 MB (live: k_exact2)
  const size_t OFF_XB   = 134217728;    // x bf16       :  32 MB (dead after k_gemm)
  const size_t OFF_TIDX = 134217728;    //   overlay: top-64 idx (2 MB)
  const size_t OFF_TACT = 136314880;    //   overlay: top-64 act (2 MB)
  const size_t OFF_WTB  = 167772160;    // W_encT bf16  :  64 MB
  const size_t OFF_PRE  = 234881024;    // pre fp16     : 256 MB
  const size_t OFF_DEF  = 503316480;    // def idx      :   2 MB
  const size_t OFF_AMB  = 505413632;    // amb idx      :   2 MB
  const size_t OFF_CNT  = 507510784;    // counts       :  64 KB -> end 507576320

  float*          WencT = (float*)(ws + OFF_WT);
  unsigned short* xb    = (unsigned short*)(ws + OFF_XB);
  unsigned short* Wtb   = (unsigned short*)(ws + OFF_WTB);
  _Float16*       pre   = (_Float16*)(ws + OFF_PRE);
  int*            didx  = (int*)(ws + OFF_DEF);
  int*            aidx  = (int*)(ws + OFF_AMB);
  int*            cnt   = (int*)(ws + OFF_CNT);
  int*            tidx  = (int*)(ws + OFF_TIDX);
  float*          tact  = (float*)(ws + OFF_TACT);

  k_convx<<<M_ROWS * K_DIM / 1024, 256, 0, stream>>>(x, xb);
  k_transpose<<<dim3(N_SAE / 32, K_DIM / 32), 256, 0, stream>>>(W_enc, WencT, Wtb);
  k_gemm<<<2048, 512, 0, stream>>>(xb, Wtb, b_enc, pre);
  k_select<<<M_ROWS, 256, 0, stream>>>((const unsigned short*)pre, didx, aidx, cnt);
  k_exact2<<<M_ROWS, 256, 0, stream>>>(x, WencT, b_enc, pre, didx, aidx, cnt, tidx, tact);
  k_decode<<<M_ROWS, 256, 0, stream>>>(W_dec, b_dec, tidx, tact, out);
}

// Round 3
// 1760.447 us; speedup vs baseline: 1.0747x; 1.0460x over previous
//
#include <hip/hip_runtime.h>

#define M_ROWS 8192
#define K_DIM  2048
#define N_SAE  16384
#define TOPK   64
#define WEPS   0.027f   // 2*eps: eps = 6*sigma_gemm(2e-3) + fp16 half-ulp(1e-3) ~ 1.3e-2

typedef __attribute__((ext_vector_type(8))) short bf16x8;
typedef __attribute__((ext_vector_type(4))) float f32x4;

__device__ __forceinline__ unsigned short f2bf(float f) {
  unsigned u = __float_as_uint(f);
  u += 0x7FFFu + ((u >> 16) & 1u);   // round-to-nearest-even
  return (unsigned short)(u >> 16);
}

__device__ __forceinline__ float key2float(unsigned k) {
  unsigned short bits = (k & 0x8000u) ? (unsigned short)(k ^ 0x8000u)
                                      : (unsigned short)(~k);
  _Float16 h;
  __builtin_memcpy(&h, &bits, 2);
  return (float)h;
}

__device__ __forceinline__ void gload16(const void* g, void* l) {
  __builtin_amdgcn_global_load_lds(
      (const __attribute__((address_space(1))) unsigned int*)g,
      (__attribute__((address_space(3))) unsigned int*)l, 16, 0, 0);
}

// ---------------- kernel 0a: x fp32 -> bf16 ----------------
__global__ __launch_bounds__(256) void k_convx(const float* __restrict__ x,
                                               unsigned short* __restrict__ xb) {
  const long i = ((long)blockIdx.x * 256 + threadIdx.x) * 4;
  float4 v = *(const float4*)(x + i);
  ushort4 o;
  o.x = f2bf(v.x); o.y = f2bf(v.y); o.z = f2bf(v.z); o.w = f2bf(v.w);
  *(ushort4*)(xb + i) = o;
}

// ---------------- kernel 0b: W_enc [K,N] -> W_encT [N,K] (f32 + bf16) ----------------
__global__ __launch_bounds__(256) void k_transpose(const float* __restrict__ W,
                                                   float* __restrict__ Wt,
                                                   unsigned short* __restrict__ Wtb) {
  __shared__ float tile[32][33];
  const int nb = blockIdx.x * 32;
  const int kb = blockIdx.y * 32;
  const int tx = threadIdx.x & 31;
  const int ty = threadIdx.x >> 5;
#pragma unroll
  for (int i = 0; i < 32; i += 8)
    tile[ty + i][tx] = W[(long)(kb + ty + i) * N_SAE + nb + tx];
  __syncthreads();
#pragma unroll
  for (int i = 0; i < 32; i += 8) {
    float v = tile[tx][ty + i];
    long o = (long)(nb + ty + i) * K_DIM + kb + tx;
    Wt[o] = v;
    Wtb[o] = f2bf(v);
  }
}

// ---------------- kernel 1: bf16 MFMA GEMM, 256x256 tile, 8-phase counted-vmcnt schedule ----------------
// pre = x @ W_enc + b_enc -> fp16.  A=[M,K] bf16 row-major, B=[N,K] bf16 (W_enc^T).
// BK=64 (128B rows). LDS: 2 buffers x (A 32KB + B 32KB) = 128 KiB.
// Swizzle (rule #21: both-sides-or-neither): storage at (row, kb) holds logical byte kb^((row&7)<<4).
//   - gload_lds dest is LINEAR (HW writes wave-uniform base + lane*16; per-lane LDS scatter ignored, m104)
//   - the involution is applied to the PER-LANE GLOBAL SOURCE address (that side IS per-lane)
//   - ds_read applies the same XOR -> each 8-lane subgroup hits 8 distinct 16B slots (conflict-free)
// 8 phases / 2 K-tiles; per phase: {ds_read subtile, 1 stage unit (2 gload_lds), bar, lgkm0+schedbar, 16 MFMA, bar}.
// vmcnt(6) only at phases 4/8 (3 stage-units = 6 loads stay in flight). Stage units follow the read partition:
//   A-P1 = rows 0-63 & 128-191 (phase-1 reads for wm=0/1), A-P2 = rows 64-127 & 192-255 (phase 3)
//   B-P1 = rows {0-31,64-95,128-159,192-223} (ni 0-1), B-P2 = +32 (ni 2-3)
__device__ __forceinline__ void mkchunk(int type, int u, int bm, int bn, int& g, int& l) {
  // type 0: A-P1, 1: A-P2, 2: B-P1, 3: B-P2;  u = linear byte index within the unit [0,16384)
  const int kb = u & 127;
  int row;
  if (type == 0)      row = (u < 8192) ? (u >> 7) : (128 + ((u - 8192) >> 7));
  else if (type == 1) row = (u < 8192) ? (64 + (u >> 7)) : (192 + ((u - 8192) >> 7));
  else if (type == 2) row = (u >> 12) * 64 + ((u >> 7) & 31);
  else                row = (u >> 12) * 64 + 32 + ((u >> 7) & 31);
  l = ((type >= 2) ? 32768 : 0) + row * 128 + kb;      // LINEAR dest (per-wave contiguous)
  const int kbs = kb ^ ((row & 7) << 4);               // inverse-swizzled per-lane global source
  g = ((type >= 2 ? bn : bm) + row) * K_DIM + (kbs >> 1);
}

__global__ __launch_bounds__(512, 2) void k_gemm(const unsigned short* __restrict__ A,
                                                 const unsigned short* __restrict__ B,
                                                 const float* __restrict__ b_enc,
                                                 _Float16* __restrict__ C) {
  __shared__ unsigned short lds[2 * 32768];   // 128 KiB
  char* lb = (char*)lds;
  const int t = threadIdx.x;
  const int lane = t & 63;
  const int w = t >> 6;
  const int wm = w >> 2, wn = w & 3;          // 2M x 4N waves, per-wave 128x64 out
  const int ml = lane & 15, kh = lane >> 4;

  // XCD-aware bijective swizzle (2048 % 8 == 0)
  const int bid = blockIdx.x;
  const int swz = (bid & 7) * 256 + (bid >> 3);
  const int bn = (swz & 63) * 256;
  const int bm = (swz >> 6) * 256;

  // per-thread stage chunks: (global elem offset, LDS byte offset) per unit, 2 chunks each
  int gA1[2], lA1[2], gA2[2], lA2[2], gB1[2], lB1[2], gB2[2], lB2[2];
  mkchunk(0, t * 16,        bm, bn, gA1[0], lA1[0]);
  mkchunk(0, t * 16 + 8192, bm, bn, gA1[1], lA1[1]);
  mkchunk(1, t * 16,        bm, bn, gA2[0], lA2[0]);
  mkchunk(1, t * 16 + 8192, bm, bn, gA2[1], lA2[1]);
  mkchunk(2, t * 16,        bm, bn, gB1[0], lB1[0]);
  mkchunk(2, t * 16 + 8192, bm, bn, gB1[1], lB1[1]);
  mkchunk(3, t * 16,        bm, bn, gB2[0], lB2[0]);
  mkchunk(3, t * 16 + 8192, bm, bn, gB2[1], lB2[1]);

  // read offsets: row&7 == ml&7 for both A and B (mi*16, wm*128, wn*64, ni*16 are 0 mod 8)
  const int swx = (ml & 7) << 4;
  const int aof0 = (wm * 128 + ml) * 128 + ((kh * 16) ^ swx);
  const int aof1 = (wm * 128 + ml) * 128 + ((64 + kh * 16) ^ swx);
  const int bof0 = 32768 + (wn * 64 + ml) * 128 + ((kh * 16) ^ swx);
  const int bof1 = 32768 + (wn * 64 + ml) * 128 + ((64 + kh * 16) ^ swx);

  f32x4 acc[8][4] = {};
  bf16x8 af[4][2], bv01[2][2], bv23[2][2];

#define STG(P, gv, lv, bb, ktc) do {                       \
    gload16(P + gv[0] + (ktc) * 64, lb + (bb) + lv[0]);    \
    gload16(P + gv[1] + (ktc) * 64, lb + (bb) + lv[1]); } while (0)

#define RD_A(CB, MB) do { _Pragma("unroll")                                          \
    for (int mi = 0; mi < 4; ++mi) {                                                 \
      af[mi][0] = *(const bf16x8*)(lb + (CB) + aof0 + ((MB) + mi) * 2048);           \
      af[mi][1] = *(const bf16x8*)(lb + (CB) + aof1 + ((MB) + mi) * 2048); } } while (0)

#define RD_B(DST, CB, NB) do { _Pragma("unroll")                                     \
    for (int ni = 0; ni < 2; ++ni) {                                                 \
      DST[ni][0] = *(const bf16x8*)(lb + (CB) + bof0 + ((NB) + ni) * 2048);          \
      DST[ni][1] = *(const bf16x8*)(lb + (CB) + bof1 + ((NB) + ni) * 2048); } } while (0)

#define MFMA_Q(BV, MB, NB) do {                                                      \
    __builtin_amdgcn_s_setprio(1);                                                   \
    _Pragma("unroll")                                                                \
    for (int mi = 0; mi < 4; ++mi) { _Pragma("unroll")                               \
      for (int ni = 0; ni < 2; ++ni) {                                               \
        acc[(MB)+mi][(NB)+ni] = __builtin_amdgcn_mfma_f32_16x16x32_bf16(             \
            af[mi][0], BV[ni][0], acc[(MB)+mi][(NB)+ni], 0, 0, 0);                   \
        acc[(MB)+mi][(NB)+ni] = __builtin_amdgcn_mfma_f32_16x16x32_bf16(             \
            af[mi][1], BV[ni][1], acc[(MB)+mi][(NB)+ni], 0, 0, 0);                   \
      } }                                                                            \
    __builtin_amdgcn_s_setprio(0); } while (0)

// rule #18: register-only MFMA can hoist past inline-asm waitcnt despite "memory";
// sched_barrier(0) immediately after is the fence. Raw s_barrier gets one too.
#define SBAR  __builtin_amdgcn_sched_barrier(0)
#define LGKM0 do { asm volatile("s_waitcnt lgkmcnt(0)" ::: "memory"); SBAR; } while (0)
#define VMC6  do { asm volatile("s_waitcnt vmcnt(6)" ::: "memory"); SBAR; } while (0)
#define BAR   do { __builtin_amdgcn_s_barrier(); SBAR; } while (0)

  // 4 phases of one K-tile from buffer CB; stages S1..S4 are the per-slot prefetches.
#define TILE(CB, S1, S2, S3, S4) do {             \
    RD_A(CB, 0); RD_B(bv01, CB, 0);               \
    S1;                                           \
    BAR; LGKM0; MFMA_Q(bv01, 0, 0); BAR;          \
    RD_B(bv23, CB, 2);                            \
    S2;                                           \
    BAR; LGKM0; MFMA_Q(bv23, 0, 2); BAR;          \
    RD_A(CB, 4);                                  \
    S3;                                           \
    BAR; LGKM0; MFMA_Q(bv23, 4, 2); BAR;          \
    S4;                                           \
    VMC6; BAR; MFMA_Q(bv01, 4, 0); BAR;           \
  } while (0)

  // prologue = virtual iter -1 slots ph2..ph8 (exact steady-state issue order)
  STG(A, gA1, lA1, 0, 0);        // A0P1(0)
  STG(B, gB1, lB1, 0, 0);        // B0P1(0)
  STG(B, gB2, lB2, 0, 0);        // B0P2(0)
  STG(A, gA2, lA2, 0, 0);        // A0P2(0)
  STG(A, gA1, lA1, 65536, 1);    // A1P1(1)
  STG(B, gB1, lB1, 65536, 1);    // B1P1(1)
  STG(B, gB2, lB2, 65536, 1);    // B1P2(1)
  VMC6;                          // drains tile-0's 4 units; 3 tile-1 units remain in flight
  BAR;

  for (int i = 0; i < 16; ++i) {
    const int o  = 2 * i + 1;
    const int c2 = (2 * i + 2 < 32) ? 2 * i + 2 : 31;  // clamped dummy on last iter:
    const int c3 = (2 * i + 3 < 32) ? 2 * i + 3 : 31;  // writes only dead/identical LDS regions
    // even tile 2i from buf0; slots: ph1 A1P2(o), ph2 A0P1(c2), ph3 B0P1(c2), ph4 B0P2(c2)
    TILE(0,
         STG(A, gA2, lA2, 65536, o),
         STG(A, gA1, lA1, 0, c2),
         STG(B, gB1, lB1, 0, c2),
         STG(B, gB2, lB2, 0, c2));
    // odd tile 2i+1 from buf1; slots: ph5 A0P2(c2), ph6 A1P1(c3), ph7 B1P1(c3), ph8 B1P2(c3)
    TILE(65536,
         STG(A, gA2, lA2, 0, c2),
         STG(A, gA1, lA1, 65536, c3),
         STG(B, gB1, lB1, 65536, c3),
         STG(B, gB2, lB2, 65536, c3));
  }
#undef TILE
#undef STG
#undef RD_A
#undef RD_B
#undef MFMA_Q

  // epilogue: C/D layout col=lane&15, row=(lane>>4)*4+reg  [m89-verified]
#pragma unroll
  for (int ni = 0; ni < 4; ++ni) {
    const int gn = bn + wn * 64 + ni * 16 + ml;
    const float bias = b_enc[gn];
#pragma unroll
    for (int mi = 0; mi < 8; ++mi) {
      const int gm0 = bm + wm * 128 + mi * 16 + kh * 4;
#pragma unroll
      for (int rr = 0; rr < 4; ++rr)
        C[(long)(gm0 + rr) * N_SAE + gn] = (_Float16)(acc[mi][ni][rr] + bias);
    }
  }
}

// ---------------- kernel 2: exact 64th-largest threshold + definite/ambiguous split ----------------
__global__ __launch_bounds__(256) void k_select(const unsigned short* __restrict__ pre,
                                                int* __restrict__ def_idx,
                                                int* __restrict__ amb_idx,
                                                int* __restrict__ counts) {
  __shared__ unsigned short keys[16384];  // 32 KB
  __shared__ unsigned int hist[256];
  __shared__ unsigned int scan[256];
  __shared__ unsigned int sc[8];
  const long row = blockIdx.x;
  const int t = threadIdx.x;
  const uint4* src = (const uint4*)(pre + row * N_SAE);
  uint4* kdst = (uint4*)keys;
#pragma unroll
  for (int i = 0; i < 8; i++) {
    uint4 v = src[i * 256 + t];
    uint4 o;
    unsigned s;
    s = v.x & 0x80008000u; o.x = v.x ^ (0x80008000u | ((s >> 15) * 0x7FFFu));
    s = v.y & 0x80008000u; o.y = v.y ^ (0x80008000u | ((s >> 15) * 0x7FFFu));
    s = v.z & 0x80008000u; o.z = v.z ^ (0x80008000u | ((s >> 15) * 0x7FFFu));
    s = v.w & 0x80008000u; o.w = v.w ^ (0x80008000u | ((s >> 15) * 0x7FFFu));
    kdst[i * 256 + t] = o;
  }
  hist[t] = 0;
  if (t < 8) sc[t] = 0;
  __syncthreads();
  for (int i = 0; i < 64; i++) {
    unsigned k = keys[i * 256 + t];
    atomicAdd(&hist[k >> 8], 1u);
  }
  __syncthreads();
  scan[t] = hist[t];
  __syncthreads();
  for (int off = 1; off < 256; off <<= 1) {   // suffix sum
    unsigned v = (t + off < 256) ? scan[t + off] : 0u;
    __syncthreads();
    scan[t] += v;
    __syncthreads();
  }
  if (scan[t] >= TOPK && (t == 255 || scan[t + 1] < TOPK)) {
    sc[0] = (unsigned)t;
    sc[1] = (t == 255) ? 0u : scan[t + 1];
  }
  __syncthreads();
  const unsigned bstar = sc[0];
  const unsigned H = sc[1];
  hist[t] = 0;
  __syncthreads();
  for (int i = 0; i < 64; i++) {
    unsigned k = keys[i * 256 + t];
    if ((k >> 8) == bstar) atomicAdd(&hist[k & 255u], 1u);
  }
  __syncthreads();
  scan[t] = hist[t];
  __syncthreads();
  for (int off = 1; off < 256; off <<= 1) {
    unsigned v = (t + off < 256) ? scan[t + off] : 0u;
    __syncthreads();
    scan[t] += v;
    __syncthreads();
  }
  if (H + scan[t] >= TOPK && (t == 255 || H + scan[t + 1] < TOPK)) sc[2] = (unsigned)t;
  __syncthreads();
  const unsigned T = (bstar << 8) | sc[2];      // exact 64th-largest fp16 key
  const float tf = key2float(T);
  const float lo = tf - WEPS;
  const float hi = tf + WEPS;
  for (int i = 0; i < 64; i++) {
    unsigned k = keys[i * 256 + t];
    float vf = key2float(k);
    if (vf > hi) {                               // provably in true top-64 (ndef <= 63)
      unsigned p = atomicAdd(&sc[3], 1u);
      def_idx[row * 64 + p] = i * 256 + t;
    } else if (vf >= lo) {                       // ambiguous: needs exact recompute
      unsigned p = atomicAdd(&sc[4], 1u);
      if (p < 64) amb_idx[row * 64 + p] = i * 256 + t;
    }
  }
  __syncthreads();
  if (t == 0) {
    counts[row * 2]     = (int)sc[3];
    counts[row * 2 + 1] = (int)(sc[4] < 64u ? sc[4] : 64u);
  }
}

// ---------------- kernel 3: f64 recompute of ambiguous set only + exact boundary ranking ----------------
__global__ __launch_bounds__(256) void k_exact2(const float* __restrict__ x,
                                                const float* __restrict__ Wt,
                                                const float* __restrict__ b_enc,
                                                const _Float16* __restrict__ pre,
                                                const int* __restrict__ def_idx,
                                                const int* __restrict__ amb_idx,
                                                const int* __restrict__ counts,
                                                int* __restrict__ tidx,
                                                float* __restrict__ tact) {
  __shared__ float xs[2048];
  __shared__ double vals[64];
  __shared__ int idxs[64];
  const int row = blockIdx.x;
  const int t = threadIdx.x;
  {
    const float4* src = (const float4*)(x + (long)row * K_DIM);
    ((float4*)xs)[t] = src[t];
    ((float4*)xs)[t + 256] = src[t + 256];
  }
  const int ndef = counts[row * 2];
  const int namb = counts[row * 2 + 1];
  if (t < 64) {
    idxs[t] = (t < namb) ? amb_idx[row * 64 + t] : -1;
    vals[t] = -1e300;
  }
  __syncthreads();
  const int wave = t >> 6, lane = t & 63;
  for (int c = wave; c < namb; c += 4) {
    const int f = idxs[c];
    const float4* w = (const float4*)(Wt + (long)f * K_DIM);
    const float4* xv4 = (const float4*)xs;
    double s = 0.0;
#pragma unroll
    for (int j = 0; j < 8; j++) {
      float4 wv = w[j * 64 + lane];
      float4 xv = xv4[j * 64 + lane];
      s += (double)wv.x * (double)xv.x;
      s += (double)wv.y * (double)xv.y;
      s += (double)wv.z * (double)xv.z;
      s += (double)wv.w * (double)xv.w;
    }
#pragma unroll
    for (int off = 32; off > 0; off >>= 1) s += __shfl_down(s, off);
    if (lane == 0) vals[c] = s + (double)b_enc[f];
  }
  __syncthreads();
  // bitonic sort descending over 64 (value, idx)
  for (int kk = 2; kk <= 64; kk <<= 1) {
    for (int j = kk >> 1; j > 0; j >>= 1) {
      if (t < 64) {
        const int p = t ^ j;
        if (p > t) {
          const bool up = ((t & kk) == 0);
          double a = vals[t], b = vals[p];
          if (up ? (a < b) : (a > b)) {
            vals[t] = b; vals[p] = a;
            int tmp = idxs[t]; idxs[t] = idxs[p]; idxs[p] = tmp;
          }
        }
      }
      __syncthreads();
    }
  }
  // outputs: ndef definite (fp16 approx values) + (64-ndef) best ambiguous (exact values)
  if (t < ndef) {
    const int f = def_idx[row * 64 + t];
    const float v = (float)pre[(long)row * N_SAE + f];
    tidx[row * TOPK + t] = f;
    tact[row * TOPK + t] = v > 0.f ? v : 0.f;
  }
  const int need = TOPK - ndef;
  if (t < need) {
    int f = idxs[t];
    double v = vals[t];
    if (f < 0) { f = 0; v = 0.0; }   // unreachable guard
    tidx[row * TOPK + ndef + t] = f;
    tact[row * TOPK + ndef + t] = (float)(v > 0.0 ? v : 0.0);
  }
}

// ---------------- kernel 4: sparse decode, recon = acts @ W_dec + b_dec ----------------
__global__ __launch_bounds__(256) void k_decode(const float* __restrict__ Wd,
                                                const float* __restrict__ b_dec,
                                                const int* __restrict__ tidx,
                                                const float* __restrict__ tact,
                                                float* __restrict__ out) {
  __shared__ int fid[TOPK];
  __shared__ float fac[TOPK];
  const int row = blockIdx.x, t = threadIdx.x;
  if (t < TOPK) {
    fid[t] = tidx[row * TOPK + t];
    fac[t] = tact[row * TOPK + t];
  }
  __syncthreads();
  float4 acc0 = ((const float4*)b_dec)[t * 2];
  float4 acc1 = ((const float4*)b_dec)[t * 2 + 1];
  for (int i = 0; i < TOPK; i++) {
    const float a = fac[i];
    const float4* w = (const float4*)(Wd + (long)fid[i] * K_DIM) + t * 2;
    float4 w0 = w[0], w1 = w[1];
    acc0.x += a * w0.x; acc0.y += a * w0.y; acc0.z += a * w0.z; acc0.w += a * w0.w;
    acc1.x += a * w1.x; acc1.y += a * w1.y; acc1.z += a * w1.z; acc1.w += a * w1.w;
  }
  float4* o = (float4*)(out + (long)row * K_DIM);
  o[t * 2] = acc0;
  o[t * 2 + 1] = acc1;
}

extern "C" void kernel_launch(void* const* d_in, const int* in_sizes, int n_in,
                              void* d_out, int out_size, void* d_ws, size_t ws_size,
                              hipStream_t stream) {
  const float* x     = (const float*)d_in[0];
  const float* W_enc = (const float*)d_in[1];
  const float* W_dec = (const float*)d_in[2];
  const float* b_enc = (const float*)d_in[3];
  const float* b_dec = (const float*)d_in[4];
  float* out = (float*)d_out;
  char* ws = (char*)d_ws;

  // layout (fits in the round-1-proven 488 MB):
  const size_t OFF_WT   = 0;            // W_encT f32   : 128 MB (live: k_exact2)
  const size_t OFF_XB   = 134217728;    // x bf16       :  32 MB (dead after k_gemm)
  const size_t OFF_TIDX = 134217728;    //   overlay: top-64 idx (2 MB)
  const size_t OFF_TACT = 136314880;    //   overlay: top-64 act (2 MB)
  const size_t OFF_WTB  = 167772160;    // W_encT bf16  :  64 MB
  const size_t OFF_PRE  = 234881024;    // pre fp16     : 256 MB
  const size_t OFF_DEF  = 503316480;    // def idx      :   2 MB
  const size_t OFF_AMB  = 505413632;    // amb idx      :   2 MB
  const size_t OFF_CNT  = 507510784;    // counts       :  64 KB -> end 507576320

  float*          WencT = (float*)(ws + OFF_WT);
  unsigned short* xb    = (unsigned short*)(ws + OFF_XB);
  unsigned short* Wtb   = (unsigned short*)(ws + OFF_WTB);
  _Float16*       pre   = (_Float16*)(ws + OFF_PRE);
  int*            didx  = (int*)(ws + OFF_DEF);
  int*            aidx  = (int*)(ws + OFF_AMB);
  int*            cnt   = (int*)(ws + OFF_CNT);
  int*            tidx  = (int*)(ws + OFF_TIDX);
  float*          tact  = (float*)(ws + OFF_TACT);

  k_convx<<<M_ROWS * K_DIM / 1024, 256, 0, stream>>>(x, xb);
  k_transpose<<<dim3(N_SAE / 32, K_DIM / 32), 256, 0, stream>>>(W_enc, WencT, Wtb);
  k_gemm<<<2048, 512, 0, stream>>>(xb, Wtb, b_enc, pre);
  k_select<<<M_ROWS, 256, 0, stream>>>((const unsigned short*)pre, didx, aidx, cnt);
  k_exact2<<<M_ROWS, 256, 0, stream>>>(x, WencT, b_enc, pre, didx, aidx, cnt, tidx, tact);
  k_decode<<<M_ROWS, 256, 0, stream>>>(W_dec, b_dec, tidx, tact, out);
}

// Round 4
// 1514.089 us; speedup vs baseline: 1.2496x; 1.1627x over previous
//
#include <hip/hip_runtime.h>

#define M_ROWS 8192
#define K_DIM  2048
#define N_SAE  16384
#define TOPK   64
#define WEPS   0.027f   // 2*eps: eps = 6*sigma_gemm(2e-3) + fp16 half-ulp(1e-3) ~ 1.3e-2

typedef __attribute__((ext_vector_type(8))) short bf16x8;
typedef __attribute__((ext_vector_type(8))) unsigned short u16x8;
typedef __attribute__((ext_vector_type(4))) float f32x4;

__device__ __forceinline__ unsigned short f2bf(float f) {
  unsigned u = __float_as_uint(f);
  u += 0x7FFFu + ((u >> 16) & 1u);   // round-to-nearest-even
  return (unsigned short)(u >> 16);
}

__device__ __forceinline__ float key2float(unsigned k) {
  unsigned short bits = (k & 0x8000u) ? (unsigned short)(k ^ 0x8000u)
                                      : (unsigned short)(~k);
  _Float16 h;
  __builtin_memcpy(&h, &bits, 2);
  return (float)h;
}

__device__ __forceinline__ void gload16(const void* g, void* l) {
  __builtin_amdgcn_global_load_lds(
      (const __attribute__((address_space(1))) unsigned int*)g,
      (__attribute__((address_space(3))) unsigned int*)l, 16, 0, 0);
}

// ---------------- kernel 0a: x fp32 -> bf16 ----------------
__global__ __launch_bounds__(256) void k_convx(const float* __restrict__ x,
                                               unsigned short* __restrict__ xb) {
  const long i = ((long)blockIdx.x * 256 + threadIdx.x) * 4;
  float4 v = *(const float4*)(x + i);
  ushort4 o;
  o.x = f2bf(v.x); o.y = f2bf(v.y); o.z = f2bf(v.z); o.w = f2bf(v.w);
  *(ushort4*)(xb + i) = o;
}

// ---------------- kernel 0c: W_dec fp32 -> bf16 (into WTB region, dead after k_gemm) ----------------
__global__ __launch_bounds__(256) void k_convw(const float* __restrict__ Wd,
                                               unsigned short* __restrict__ Wdb) {
  const long i = ((long)blockIdx.x * 256 + threadIdx.x) * 4;
  float4 v = *(const float4*)(Wd + i);
  ushort4 o;
  o.x = f2bf(v.x); o.y = f2bf(v.y); o.z = f2bf(v.z); o.w = f2bf(v.w);
  *(ushort4*)(Wdb + i) = o;
}

// ---------------- kernel 0b: W_enc [K,N] -> W_encT [N,K] (f32 + bf16) ----------------
__global__ __launch_bounds__(256) void k_transpose(const float* __restrict__ W,
                                                   float* __restrict__ Wt,
                                                   unsigned short* __restrict__ Wtb) {
  __shared__ float tile[32][33];
  const int nb = blockIdx.x * 32;
  const int kb = blockIdx.y * 32;
  const int tx = threadIdx.x & 31;
  const int ty = threadIdx.x >> 5;
#pragma unroll
  for (int i = 0; i < 32; i += 8)
    tile[ty + i][tx] = W[(long)(kb + ty + i) * N_SAE + nb + tx];
  __syncthreads();
#pragma unroll
  for (int i = 0; i < 32; i += 8) {
    float v = tile[tx][ty + i];
    long o = (long)(nb + ty + i) * K_DIM + kb + tx;
    Wt[o] = v;
    Wtb[o] = f2bf(v);
  }
}

// ---------------- kernel 1: bf16 MFMA GEMM, 256x256 tile, 8-phase counted-vmcnt schedule ----------------
// pre = x @ W_enc + b_enc -> fp16.  A=[M,K] bf16 row-major, B=[N,K] bf16 (W_enc^T).
// BK=64 (128B rows). LDS: 2 buffers x (A 32KB + B 32KB) = 128 KiB.
// Swizzle (rule #21: both-sides-or-neither): storage at (row, kb) holds logical byte kb^((row&7)<<4).
//   - gload_lds dest is LINEAR (HW writes wave-uniform base + lane*16; per-lane LDS scatter ignored, m104)
//   - the involution is applied to the PER-LANE GLOBAL SOURCE address (that side IS per-lane)
//   - ds_read applies the same XOR -> each 8-lane subgroup hits 8 distinct 16B slots (conflict-free)
// 8 phases / 2 K-tiles; per phase: {ds_read subtile, 1 stage unit (2 gload_lds), bar, lgkm0+schedbar, 16 MFMA, bar}.
// vmcnt(6) only at phases 4/8 (3 stage-units = 6 loads stay in flight). Stage units follow the read partition:
//   A-P1 = rows 0-63 & 128-191 (phase-1 reads for wm=0/1), A-P2 = rows 64-127 & 192-255 (phase 3)
//   B-P1 = rows {0-31,64-95,128-159,192-223} (ni 0-1), B-P2 = +32 (ni 2-3)
__device__ __forceinline__ void mkchunk(int type, int u, int bm, int bn, int& g, int& l) {
  // type 0: A-P1, 1: A-P2, 2: B-P1, 3: B-P2;  u = linear byte index within the unit [0,16384)
  const int kb = u & 127;
  int row;
  if (type == 0)      row = (u < 8192) ? (u >> 7) : (128 + ((u - 8192) >> 7));
  else if (type == 1) row = (u < 8192) ? (64 + (u >> 7)) : (192 + ((u - 8192) >> 7));
  else if (type == 2) row = (u >> 12) * 64 + ((u >> 7) & 31);
  else                row = (u >> 12) * 64 + 32 + ((u >> 7) & 31);
  l = ((type >= 2) ? 32768 : 0) + row * 128 + kb;      // LINEAR dest (per-wave contiguous)
  const int kbs = kb ^ ((row & 7) << 4);               // inverse-swizzled per-lane global source
  g = ((type >= 2 ? bn : bm) + row) * K_DIM + (kbs >> 1);
}

__global__ __launch_bounds__(512, 2) void k_gemm(const unsigned short* __restrict__ A,
                                                 const unsigned short* __restrict__ B,
                                                 const float* __restrict__ b_enc,
                                                 _Float16* __restrict__ C) {
  __shared__ unsigned short lds[2 * 32768];   // 128 KiB
  char* lb = (char*)lds;
  const int t = threadIdx.x;
  const int lane = t & 63;
  const int w = t >> 6;
  const int wm = w >> 2, wn = w & 3;          // 2M x 4N waves, per-wave 128x64 out
  const int ml = lane & 15, kh = lane >> 4;

  // XCD-aware bijective swizzle (2048 % 8 == 0)
  const int bid = blockIdx.x;
  const int swz = (bid & 7) * 256 + (bid >> 3);
  const int bn = (swz & 63) * 256;
  const int bm = (swz >> 6) * 256;

  // per-thread stage chunks: (global elem offset, LDS byte offset) per unit, 2 chunks each
  int gA1[2], lA1[2], gA2[2], lA2[2], gB1[2], lB1[2], gB2[2], lB2[2];
  mkchunk(0, t * 16,        bm, bn, gA1[0], lA1[0]);
  mkchunk(0, t * 16 + 8192, bm, bn, gA1[1], lA1[1]);
  mkchunk(1, t * 16,        bm, bn, gA2[0], lA2[0]);
  mkchunk(1, t * 16 + 8192, bm, bn, gA2[1], lA2[1]);
  mkchunk(2, t * 16,        bm, bn, gB1[0], lB1[0]);
  mkchunk(2, t * 16 + 8192, bm, bn, gB1[1], lB1[1]);
  mkchunk(3, t * 16,        bm, bn, gB2[0], lB2[0]);
  mkchunk(3, t * 16 + 8192, bm, bn, gB2[1], lB2[1]);

  // read offsets: row&7 == ml&7 for both A and B (mi*16, wm*128, wn*64, ni*16 are 0 mod 8)
  const int swx = (ml & 7) << 4;
  const int aof0 = (wm * 128 + ml) * 128 + ((kh * 16) ^ swx);
  const int aof1 = (wm * 128 + ml) * 128 + ((64 + kh * 16) ^ swx);
  const int bof0 = 32768 + (wn * 64 + ml) * 128 + ((kh * 16) ^ swx);
  const int bof1 = 32768 + (wn * 64 + ml) * 128 + ((64 + kh * 16) ^ swx);

  f32x4 acc[8][4] = {};
  bf16x8 af[4][2], bv01[2][2], bv23[2][2];

#define STG(P, gv, lv, bb, ktc) do {                       \
    gload16(P + gv[0] + (ktc) * 64, lb + (bb) + lv[0]);    \
    gload16(P + gv[1] + (ktc) * 64, lb + (bb) + lv[1]); } while (0)

#define RD_A(CB, MB) do { _Pragma("unroll")                                          \
    for (int mi = 0; mi < 4; ++mi) {                                                 \
      af[mi][0] = *(const bf16x8*)(lb + (CB) + aof0 + ((MB) + mi) * 2048);           \
      af[mi][1] = *(const bf16x8*)(lb + (CB) + aof1 + ((MB) + mi) * 2048); } } while (0)

#define RD_B(DST, CB, NB) do { _Pragma("unroll")                                     \
    for (int ni = 0; ni < 2; ++ni) {                                                 \
      DST[ni][0] = *(const bf16x8*)(lb + (CB) + bof0 + ((NB) + ni) * 2048);          \
      DST[ni][1] = *(const bf16x8*)(lb + (CB) + bof1 + ((NB) + ni) * 2048); } } while (0)

#define MFMA_Q(BV, MB, NB) do {                                                      \
    __builtin_amdgcn_s_setprio(1);                                                   \
    _Pragma("unroll")                                                                \
    for (int mi = 0; mi < 4; ++mi) { _Pragma("unroll")                               \
      for (int ni = 0; ni < 2; ++ni) {                                               \
        acc[(MB)+mi][(NB)+ni] = __builtin_amdgcn_mfma_f32_16x16x32_bf16(             \
            af[mi][0], BV[ni][0], acc[(MB)+mi][(NB)+ni], 0, 0, 0);                   \
        acc[(MB)+mi][(NB)+ni] = __builtin_amdgcn_mfma_f32_16x16x32_bf16(             \
            af[mi][1], BV[ni][1], acc[(MB)+mi][(NB)+ni], 0, 0, 0);                   \
      } }                                                                            \
    __builtin_amdgcn_s_setprio(0); } while (0)

// rule #18: register-only MFMA can hoist past inline-asm waitcnt despite "memory";
// sched_barrier(0) immediately after is the fence. Raw s_barrier gets one too.
#define SBAR  __builtin_amdgcn_sched_barrier(0)
#define LGKM0 do { asm volatile("s_waitcnt lgkmcnt(0)" ::: "memory"); SBAR; } while (0)
#define VMC6  do { asm volatile("s_waitcnt vmcnt(6)" ::: "memory"); SBAR; } while (0)
#define BAR   do { __builtin_amdgcn_s_barrier(); SBAR; } while (0)

  // 4 phases of one K-tile from buffer CB; stages S1..S4 are the per-slot prefetches.
#define TILE(CB, S1, S2, S3, S4) do {             \
    RD_A(CB, 0); RD_B(bv01, CB, 0);               \
    S1;                                           \
    BAR; LGKM0; MFMA_Q(bv01, 0, 0); BAR;          \
    RD_B(bv23, CB, 2);                            \
    S2;                                           \
    BAR; LGKM0; MFMA_Q(bv23, 0, 2); BAR;          \
    RD_A(CB, 4);                                  \
    S3;                                           \
    BAR; LGKM0; MFMA_Q(bv23, 4, 2); BAR;          \
    S4;                                           \
    VMC6; BAR; MFMA_Q(bv01, 4, 0); BAR;           \
  } while (0)

  // prologue = virtual iter -1 slots ph2..ph8 (exact steady-state issue order)
  STG(A, gA1, lA1, 0, 0);        // A0P1(0)
  STG(B, gB1, lB1, 0, 0);        // B0P1(0)
  STG(B, gB2, lB2, 0, 0);        // B0P2(0)
  STG(A, gA2, lA2, 0, 0);        // A0P2(0)
  STG(A, gA1, lA1, 65536, 1);    // A1P1(1)
  STG(B, gB1, lB1, 65536, 1);    // B1P1(1)
  STG(B, gB2, lB2, 65536, 1);    // B1P2(1)
  VMC6;                          // drains tile-0's 4 units; 3 tile-1 units remain in flight
  BAR;

  for (int i = 0; i < 16; ++i) {
    const int o  = 2 * i + 1;
    const int c2 = (2 * i + 2 < 32) ? 2 * i + 2 : 31;  // clamped dummy on last iter:
    const int c3 = (2 * i + 3 < 32) ? 2 * i + 3 : 31;  // writes only dead/identical LDS regions
    // even tile 2i from buf0; slots: ph1 A1P2(o), ph2 A0P1(c2), ph3 B0P1(c2), ph4 B0P2(c2)
    TILE(0,
         STG(A, gA2, lA2, 65536, o),
         STG(A, gA1, lA1, 0, c2),
         STG(B, gB1, lB1, 0, c2),
         STG(B, gB2, lB2, 0, c2));
    // odd tile 2i+1 from buf1; slots: ph5 A0P2(c2), ph6 A1P1(c3), ph7 B1P1(c3), ph8 B1P2(c3)
    TILE(65536,
         STG(A, gA2, lA2, 0, c2),
         STG(A, gA1, lA1, 65536, c3),
         STG(B, gB1, lB1, 65536, c3),
         STG(B, gB2, lB2, 65536, c3));
  }
#undef TILE
#undef STG
#undef RD_A
#undef RD_B
#undef MFMA_Q

  // epilogue: C/D layout col=lane&15, row=(lane>>4)*4+reg  [m89-verified]
#pragma unroll
  for (int ni = 0; ni < 4; ++ni) {
    const int gn = bn + wn * 64 + ni * 16 + ml;
    const float bias = b_enc[gn];
#pragma unroll
    for (int mi = 0; mi < 8; ++mi) {
      const int gm0 = bm + wm * 128 + mi * 16 + kh * 4;
#pragma unroll
      for (int rr = 0; rr < 4; ++rr)
        C[(long)(gm0 + rr) * N_SAE + gn] = (_Float16)(acc[mi][ni][rr] + bias);
    }
  }
}

// ---------------- kernel 2: exact 64th-largest threshold + definite/ambiguous split ----------------
__global__ __launch_bounds__(256) void k_select(const unsigned short* __restrict__ pre,
                                                int* __restrict__ def_idx,
                                                int* __restrict__ amb_idx,
                                                int* __restrict__ counts) {
  __shared__ unsigned short keys[16384];  // 32 KB
  __shared__ unsigned int hist[256];
  __shared__ unsigned int scan[256];
  __shared__ unsigned int sc[8];
  const long row = blockIdx.x;
  const int t = threadIdx.x;
  const uint4* src = (const uint4*)(pre + row * N_SAE);
  uint4* kdst = (uint4*)keys;
#pragma unroll
  for (int i = 0; i < 8; i++) {
    uint4 v = src[i * 256 + t];
    uint4 o;
    unsigned s;
    s = v.x & 0x80008000u; o.x = v.x ^ (0x80008000u | ((s >> 15) * 0x7FFFu));
    s = v.y & 0x80008000u; o.y = v.y ^ (0x80008000u | ((s >> 15) * 0x7FFFu));
    s = v.z & 0x80008000u; o.z = v.z ^ (0x80008000u | ((s >> 15) * 0x7FFFu));
    s = v.w & 0x80008000u; o.w = v.w ^ (0x80008000u | ((s >> 15) * 0x7FFFu));
    kdst[i * 256 + t] = o;
  }
  hist[t] = 0;
  if (t < 8) sc[t] = 0;
  __syncthreads();
  for (int i = 0; i < 64; i++) {
    unsigned k = keys[i * 256 + t];
    atomicAdd(&hist[k >> 8], 1u);
  }
  __syncthreads();
  scan[t] = hist[t];
  __syncthreads();
  for (int off = 1; off < 256; off <<= 1) {   // suffix sum
    unsigned v = (t + off < 256) ? scan[t + off] : 0u;
    __syncthreads();
    scan[t] += v;
    __syncthreads();
  }
  if (scan[t] >= TOPK && (t == 255 || scan[t + 1] < TOPK)) {
    sc[0] = (unsigned)t;
    sc[1] = (t == 255) ? 0u : scan[t + 1];
  }
  __syncthreads();
  const unsigned bstar = sc[0];
  const unsigned H = sc[1];
  hist[t] = 0;
  __syncthreads();
  for (int i = 0; i < 64; i++) {
    unsigned k = keys[i * 256 + t];
    if ((k >> 8) == bstar) atomicAdd(&hist[k & 255u], 1u);
  }
  __syncthreads();
  scan[t] = hist[t];
  __syncthreads();
  for (int off = 1; off < 256; off <<= 1) {
    unsigned v = (t + off < 256) ? scan[t + off] : 0u;
    __syncthreads();
    scan[t] += v;
    __syncthreads();
  }
  if (H + scan[t] >= TOPK && (t == 255 || H + scan[t + 1] < TOPK)) sc[2] = (unsigned)t;
  __syncthreads();
  const unsigned T = (bstar << 8) | sc[2];      // exact 64th-largest fp16 key
  const float tf = key2float(T);
  const float lo = tf - WEPS;
  const float hi = tf + WEPS;
  for (int i = 0; i < 64; i++) {
    unsigned k = keys[i * 256 + t];
    float vf = key2float(k);
    if (vf > hi) {                               // provably in true top-64 (ndef <= 63)
      unsigned p = atomicAdd(&sc[3], 1u);
      def_idx[row * 64 + p] = i * 256 + t;
    } else if (vf >= lo) {                       // ambiguous: needs exact recompute
      unsigned p = atomicAdd(&sc[4], 1u);
      if (p < 64) amb_idx[row * 64 + p] = i * 256 + t;
    }
  }
  __syncthreads();
  if (t == 0) {
    counts[row * 2]     = (int)sc[3];
    counts[row * 2 + 1] = (int)(sc[4] < 64u ? sc[4] : 64u);
  }
}

// ---------------- kernel 3: f64 recompute of ambiguous set only + exact boundary ranking ----------------
__global__ __launch_bounds__(256) void k_exact2(const float* __restrict__ x,
                                                const float* __restrict__ Wt,
                                                const float* __restrict__ b_enc,
                                                const _Float16* __restrict__ pre,
                                                const int* __restrict__ def_idx,
                                                const int* __restrict__ amb_idx,
                                                const int* __restrict__ counts,
                                                int* __restrict__ tidx,
                                                float* __restrict__ tact) {
  __shared__ float xs[2048];
  __shared__ double vals[64];
  __shared__ int idxs[64];
  const int row = blockIdx.x;
  const int t = threadIdx.x;
  {
    const float4* src = (const float4*)(x + (long)row * K_DIM);
    ((float4*)xs)[t] = src[t];
    ((float4*)xs)[t + 256] = src[t + 256];
  }
  const int ndef = counts[row * 2];
  const int namb = counts[row * 2 + 1];
  if (t < 64) {
    idxs[t] = (t < namb) ? amb_idx[row * 64 + t] : -1;
    vals[t] = -1e300;
  }
  __syncthreads();
  const int wave = t >> 6, lane = t & 63;
  for (int c = wave; c < namb; c += 4) {
    const int f = idxs[c];
    const float4* w = (const float4*)(Wt + (long)f * K_DIM);
    const float4* xv4 = (const float4*)xs;
    double s = 0.0;
#pragma unroll
    for (int j = 0; j < 8; j++) {
      float4 wv = w[j * 64 + lane];
      float4 xv = xv4[j * 64 + lane];
      s += (double)wv.x * (double)xv.x;
      s += (double)wv.y * (double)xv.y;
      s += (double)wv.z * (double)xv.z;
      s += (double)wv.w * (double)xv.w;
    }
#pragma unroll
    for (int off = 32; off > 0; off >>= 1) s += __shfl_down(s, off);
    if (lane == 0) vals[c] = s + (double)b_enc[f];
  }
  __syncthreads();
  // bitonic sort descending over 64 (value, idx)
  for (int kk = 2; kk <= 64; kk <<= 1) {
    for (int j = kk >> 1; j > 0; j >>= 1) {
      if (t < 64) {
        const int p = t ^ j;
        if (p > t) {
          const bool up = ((t & kk) == 0);
          double a = vals[t], b = vals[p];
          if (up ? (a < b) : (a > b)) {
            vals[t] = b; vals[p] = a;
            int tmp = idxs[t]; idxs[t] = idxs[p]; idxs[p] = tmp;
          }
        }
      }
      __syncthreads();
    }
  }
  // outputs: ndef definite (fp16 approx values) + (64-ndef) best ambiguous (exact values)
  if (t < ndef) {
    const int f = def_idx[row * 64 + t];
    const float v = (float)pre[(long)row * N_SAE + f];
    tidx[row * TOPK + t] = f;
    tact[row * TOPK + t] = v > 0.f ? v : 0.f;
  }
  const int need = TOPK - ndef;
  if (t < need) {
    int f = idxs[t];
    double v = vals[t];
    if (f < 0) { f = 0; v = 0.0; }   // unreachable guard
    tidx[row * TOPK + ndef + t] = f;
    tact[row * TOPK + ndef + t] = (float)(v > 0.0 ? v : 0.0);
  }
}

// ---------------- kernel 4: sparse decode (bf16 W_dec), recon = acts @ W_dec + b_dec ----------------
// W_dec bf16 = 64 MB -> L3-resident (vs 128 MB f32 at ~50% HBM miss). Accumulate f32.
__global__ __launch_bounds__(256) void k_decode(const unsigned short* __restrict__ Wdb,
                                                const float* __restrict__ b_dec,
                                                const int* __restrict__ tidx,
                                                const float* __restrict__ tact,
                                                float* __restrict__ out) {
  __shared__ int fid[TOPK];
  __shared__ float fac[TOPK];
  const int row = blockIdx.x, t = threadIdx.x;
  if (t < TOPK) {
    fid[t] = tidx[row * TOPK + t];
    fac[t] = tact[row * TOPK + t];
  }
  __syncthreads();
  const float4 b0 = ((const float4*)b_dec)[t * 2];
  const float4 b1 = ((const float4*)b_dec)[t * 2 + 1];
  float acc[8] = {b0.x, b0.y, b0.z, b0.w, b1.x, b1.y, b1.z, b1.w};
  for (int i = 0; i < TOPK; i++) {
    const float a = fac[i];
    u16x8 wv = *(const u16x8*)(Wdb + (long)fid[i] * K_DIM + t * 8);
#pragma unroll
    for (int j = 0; j < 8; j++)
      acc[j] += a * __uint_as_float(((unsigned)wv[j]) << 16);
  }
  float4 o0 = {acc[0], acc[1], acc[2], acc[3]};
  float4 o1 = {acc[4], acc[5], acc[6], acc[7]};
  float4* o = (float4*)(out + (long)row * K_DIM);
  o[t * 2] = o0;
  o[t * 2 + 1] = o1;
}

extern "C" void kernel_launch(void* const* d_in, const int* in_sizes, int n_in,
                              void* d_out, int out_size, void* d_ws, size_t ws_size,
                              hipStream_t stream) {
  const float* x     = (const float*)d_in[0];
  const float* W_enc = (const float*)d_in[1];
  const float* W_dec = (const float*)d_in[2];
  const float* b_enc = (const float*)d_in[3];
  const float* b_dec = (const float*)d_in[4];
  float* out = (float*)d_out;
  char* ws = (char*)d_ws;

  // layout (fits in the round-1-proven 488 MB):
  const size_t OFF_WT   = 0;            // W_encT f32   : 128 MB (live: k_exact2)
  const size_t OFF_XB   = 134217728;    // x bf16       :  32 MB (dead after k_gemm)
  const size_t OFF_TIDX = 134217728;    //   overlay: top-64 idx (2 MB)
  const size_t OFF_TACT = 136314880;    //   overlay: top-64 act (2 MB)
  const size_t OFF_WTB  = 167772160;    // W_encT bf16  :  64 MB (dead after k_gemm; reused: W_dec bf16)
  const size_t OFF_PRE  = 234881024;    // pre fp16     : 256 MB
  const size_t OFF_DEF  = 503316480;    // def idx      :   2 MB
  const size_t OFF_AMB  = 505413632;    // amb idx      :   2 MB
  const size_t OFF_CNT  = 507510784;    // counts       :  64 KB -> end 507576320

  float*          WencT = (float*)(ws + OFF_WT);
  unsigned short* xb    = (unsigned short*)(ws + OFF_XB);
  unsigned short* Wtb   = (unsigned short*)(ws + OFF_WTB);
  unsigned short* Wdb   = (unsigned short*)(ws + OFF_WTB);  // overlay after k_gemm
  _Float16*       pre   = (_Float16*)(ws + OFF_PRE);
  int*            didx  = (int*)(ws + OFF_DEF);
  int*            aidx  = (int*)(ws + OFF_AMB);
  int*            cnt   = (int*)(ws + OFF_CNT);
  int*            tidx  = (int*)(ws + OFF_TIDX);
  float*          tact  = (float*)(ws + OFF_TACT);

  k_convx<<<M_ROWS * K_DIM / 1024, 256, 0, stream>>>(x, xb);
  k_transpose<<<dim3(N_SAE / 32, K_DIM / 32), 256, 0, stream>>>(W_enc, WencT, Wtb);
  k_gemm<<<2048, 512, 0, stream>>>(xb, Wtb, b_enc, pre);
  k_convw<<<(long)N_SAE * K_DIM / 1024, 256, 0, stream>>>(W_dec, Wdb);  // WTB dead after k_gemm
  k_select<<<M_ROWS, 256, 0, stream>>>((const unsigned short*)pre, didx, aidx, cnt);
  k_exact2<<<M_ROWS, 256, 0, stream>>>(x, WencT, b_enc, pre, didx, aidx, cnt, tidx, tact);
  k_decode<<<M_ROWS, 256, 0, stream>>>(Wdb, b_dec, tidx, tact, out);
}